// Round 1
// baseline (103.206 us; speedup 1.0000x reference)
//
#include <hip/hip_runtime.h>
#include <stdint.h>

typedef unsigned short u16;
typedef unsigned int u32;
typedef __attribute__((ext_vector_type(8))) short short8;
typedef __attribute__((ext_vector_type(4))) float float4v;

#define Bb 4
#define Ss 256
#define Hh 768
#define NALL 64

// Inputs/outputs are FP32 (reference dtype; established r7).

__device__ __forceinline__ float b2f(u16 h) {
    u32 u = ((u32)h) << 16;
    float f;
    __builtin_memcpy(&f, &u, 4);
    return f;
}
__device__ __forceinline__ u16 f2b(float f) {
    u32 u;
    __builtin_memcpy(&u, &f, 4);
    u = (u + 0x7fffu + ((u >> 16) & 1u)) >> 16;  // RNE
    return (u16)u;
}

// ---- K0: prep — all units independent ----
//  [0,2304):    basicT[q][o][i] = bf16(basic[q][i][o])   (32x32 LDS tiles)
//  [2304,3328): coefC[b,k][i][j] build (hist + fp32 relw)
//  [3328,4096): hbf  = bf16(h)      (float4 -> 4x bf16)
//  [4096,4672): swbf = bf16(selfw)
__global__ __launch_bounds__(256) void k_prep(const float* __restrict__ h,
                                              const int* __restrict__ rels,
                                              const float* __restrict__ basic,
                                              const float* __restrict__ relw,
                                              const float* __restrict__ selfw,
                                              u16* __restrict__ basicT,
                                              u16* __restrict__ coefC,
                                              u16* __restrict__ hbf,
                                              u16* __restrict__ swbf) {
    __shared__ u16 tile[32][34];   // pad 34: transposed read stride 17 banks -> conflict-free
    __shared__ float srelw[256];
    __shared__ u32 hist[NALL];
    const int z = blockIdx.x;
    const int t = threadIdx.x;

    if (z < 2304) {                     // basic transpose + cvt
        const int q = z / 576, rem = z % 576;
        const int i0 = (rem % 24) * 32, o0 = (rem / 24) * 32;
        const int tx = t & 31, ty = t >> 5;   // 32 x 8
        const size_t base = (size_t)q * Hh * Hh;
#pragma unroll
        for (int r = 0; r < 4; ++r)
            tile[ty + 8 * r][tx] = f2b(basic[base + (size_t)(i0 + ty + 8 * r) * Hh + o0 + tx]);
        __syncthreads();
#pragma unroll
        for (int r = 0; r < 4; ++r)
            basicT[base + (size_t)(o0 + ty + 8 * r) * Hh + i0 + tx] = tile[tx][ty + 8 * r];
    } else if (z < 3328) {              // coefC build: one block per (b,i)
        const int r = z - 2304;
        const int i = r & 255, b = r >> 8;
        srelw[t] = relw[t];
        if (t < NALL) hist[t] = 0u;
        __syncthreads();
        const int rfw = rels[(b * Ss + i) * Ss + t];  // rels[b,i,t]
        const int rcl = rels[(b * Ss + t) * Ss + i];  // rels[b,t,i]
        if (rfw > 0) atomicAdd(&hist[rfw], 1u);
        if (rcl > 0) atomicAdd(&hist[rcl + 32], 1u);
        __syncthreads();
        float c0 = 0.f, c1 = 0.f, c2 = 0.f, c3 = 0.f;
        if (rfw > 0) {
            const float inv = 1.0f / (float)hist[rfw];
            c0 += srelw[rfw * 4 + 0] * inv; c1 += srelw[rfw * 4 + 1] * inv;
            c2 += srelw[rfw * 4 + 2] * inv; c3 += srelw[rfw * 4 + 3] * inv;
        }
        if (rcl > 0) {
            const int rr = rcl + 32;
            const float inv = 1.0f / (float)hist[rr];
            c0 += srelw[rr * 4 + 0] * inv; c1 += srelw[rr * 4 + 1] * inv;
            c2 += srelw[rr * 4 + 2] * inv; c3 += srelw[rr * 4 + 3] * inv;
        }
        const size_t base = ((size_t)(b * 4) * Ss + i) * Ss + t;
        coefC[base] = f2b(c0);
        coefC[base + (size_t)Ss * Ss] = f2b(c1);
        coefC[base + (size_t)2 * Ss * Ss] = f2b(c2);
        coefC[base + (size_t)3 * Ss * Ss] = f2b(c3);
    } else if (z < 4096) {              // h cvt, 4 elems/thread
        const size_t i = ((size_t)(z - 3328) * 256 + t) * 4;
        const float4 v = *(const float4*)(h + i);
        u32 lo = (u32)f2b(v.x) | ((u32)f2b(v.y) << 16);
        u32 hi = (u32)f2b(v.z) | ((u32)f2b(v.w) << 16);
        *(uint2*)(hbf + i) = make_uint2(lo, hi);
    } else {                            // selfw cvt
        const size_t i = ((size_t)(z - 4096) * 256 + t) * 4;
        const float4 v = *(const float4*)(selfw + i);
        u32 lo = (u32)f2b(v.x) | ((u32)f2b(v.y) << 16);
        u32 hi = (u32)f2b(v.z) | ((u32)f2b(v.w) << 16);
        *(uint2*)(swbf + i) = make_uint2(lo, hi);
    }
}

// ---- K1: two flavors, both 64x64 tiles, K=768 (12 steps) ----
//  z <  768: Gt[bk][o][j] = sum_i basicT[q][o][i] * hbf[b][j][i]   (bf16 out)
//  z >= 768: out[b][i][o] = sum_p hbf[b][i][p] * swbf[o][p]        (fp32 out, self layer)
// Waves arranged 2x2 (32x32 quadrant each): 8 ds_read_b128 per 8 MFMA per K-step
// (was 10 with 16x64 strips) — LDS pipe is the critical resource here.
__global__ __launch_bounds__(256, 4) void k_mid(const u16* __restrict__ basicT,
                                                const u16* __restrict__ hbf,
                                                const u16* __restrict__ swbf,
                                                u16* __restrict__ Gt,
                                                float* __restrict__ out) {
    __shared__ __align__(16) u16 As[64 * 72];
    __shared__ __align__(16) u16 Bs[64 * 72];
    const int z = blockIdx.x;
    const int t = threadIdx.x;
    const int row = t >> 2, kk = (t & 3) * 16;
    const int w = t >> 6, l = t & 63, quad = l >> 4, l16 = l & 15;
    const int wr = (w >> 1) * 32, wc = (w & 1) * 32;   // 2x2 wave quadrants

    const bool selfF = (z >= 768);
    const u16* aB;
    const u16* bB;
    size_t stBase;
    if (!selfF) {
        const int o0 = (z % 12) * 64, j0 = ((z / 12) % 4) * 64, bk = z / 48;
        const int b = bk >> 2, q = bk & 3;
        aB = basicT + ((size_t)q * Hh + o0 + row) * Hh + kk;
        bB = hbf + ((size_t)b * Ss + j0 + row) * Hh + kk;
        stBase = ((size_t)bk * Hh + o0) * Ss + j0;
    } else {
        const int zz = z - 768;
        const int ot = zz % 12, it = (zz / 12) % 4, b = zz / 48;
        aB = hbf + ((size_t)b * Ss + it * 64 + row) * Hh + kk;
        bB = swbf + (size_t)(ot * 64 + row) * Hh + kk;
        stBase = ((size_t)b * Ss + it * 64) * Hh + ot * 64;
    }

    float4v acc[2][2];
#pragma unroll
    for (int m = 0; m < 2; ++m)
#pragma unroll
        for (int n = 0; n < 2; ++n) acc[m][n] = (float4v){0.f, 0.f, 0.f, 0.f};
    uint4 sa0 = *(const uint4*)aB, sa1 = *(const uint4*)(aB + 8);
    uint4 sb0 = *(const uint4*)bB, sb1 = *(const uint4*)(bB + 8);

    for (int s = 0; s < 12; ++s) {
        __syncthreads();
        *(uint4*)(&As[row * 72 + kk]) = sa0;
        *(uint4*)(&As[row * 72 + kk + 8]) = sa1;
        *(uint4*)(&Bs[row * 72 + kk]) = sb0;
        *(uint4*)(&Bs[row * 72 + kk + 8]) = sb1;
        __syncthreads();
        if (s + 1 < 12) {
            sa0 = *(const uint4*)(aB + (s + 1) * 64);
            sa1 = *(const uint4*)(aB + (s + 1) * 64 + 8);
            sb0 = *(const uint4*)(bB + (s + 1) * 64);
            sb1 = *(const uint4*)(bB + (s + 1) * 64 + 8);
        }
#pragma unroll
        for (int k2 = 0; k2 < 64; k2 += 32) {
            const int ko = k2 + quad * 8;
            const short8 fa0 = *(const short8*)(&As[(wr + l16) * 72 + ko]);
            const short8 fa1 = *(const short8*)(&As[(wr + 16 + l16) * 72 + ko]);
            const short8 fb0 = *(const short8*)(&Bs[(wc + l16) * 72 + ko]);
            const short8 fb1 = *(const short8*)(&Bs[(wc + 16 + l16) * 72 + ko]);
            acc[0][0] = __builtin_amdgcn_mfma_f32_16x16x32_bf16(fa0, fb0, acc[0][0], 0, 0, 0);
            acc[0][1] = __builtin_amdgcn_mfma_f32_16x16x32_bf16(fa0, fb1, acc[0][1], 0, 0, 0);
            acc[1][0] = __builtin_amdgcn_mfma_f32_16x16x32_bf16(fa1, fb0, acc[1][0], 0, 0, 0);
            acc[1][1] = __builtin_amdgcn_mfma_f32_16x16x32_bf16(fa1, fb1, acc[1][1], 0, 0, 0);
        }
    }

#pragma unroll
    for (int m = 0; m < 2; ++m)
#pragma unroll
        for (int n = 0; n < 2; ++n)
#pragma unroll
            for (int r = 0; r < 4; ++r) {
                const int rowl = wr + 16 * m + quad * 4 + r;   // D row = A side
                const int coll = wc + 16 * n + l16;            // D col = B side
                if (!selfF)
                    Gt[stBase + (size_t)rowl * Ss + coll] = f2b(acc[m][n][r]);
                else
                    out[stBase + (size_t)rowl * Hh + coll] = acc[m][n][r];
            }
}

// ---- K2: out[b][i][o] += sum_q coefC[b,q][i]·Gt[b,q][o]  (K=4*256, 16 steps) ----
// self layer already in `out` from k_mid; epilogue is fp32 read-modify-write.
__global__ __launch_bounds__(256, 4) void k_phase2(const u16* __restrict__ coefC,
                                                   const u16* __restrict__ Gt,
                                                   float* __restrict__ out) {
    __shared__ __align__(16) u16 As[64 * 72];
    __shared__ __align__(16) u16 Bs[64 * 72];
    const int z = blockIdx.x;           // 12 (o-tile) x 4 (i-tile) x 4 (b)
    const int ot = z % 12, it = (z / 12) % 4, b = z / 48;
    const int t = threadIdx.x;
    const int row = t >> 2, kk = (t & 3) * 16;
    const int w = t >> 6, l = t & 63, quad = l >> 4, l16 = l & 15;
    const int wr = (w >> 1) * 32, wc = (w & 1) * 32;
    const int b4 = b * 4, i0 = it * 64, o0 = ot * 64;

    auto aa = [&](int s) -> const u16* {
        return coefC + ((size_t)(b4 + (s >> 2)) * Ss + i0 + row) * Ss + (s & 3) * 64 + kk;
    };
    auto bb = [&](int s) -> const u16* {
        return Gt + ((size_t)(b4 + (s >> 2)) * Hh + o0 + row) * Ss + (s & 3) * 64 + kk;
    };
    const size_t stBase = ((size_t)b * Ss + i0) * Hh + o0;

    float4v acc[2][2];
#pragma unroll
    for (int m = 0; m < 2; ++m)
#pragma unroll
        for (int n = 0; n < 2; ++n) acc[m][n] = (float4v){0.f, 0.f, 0.f, 0.f};
    uint4 sa0 = *(const uint4*)aa(0);
    uint4 sa1 = *(const uint4*)(aa(0) + 8);
    uint4 sb0 = *(const uint4*)bb(0);
    uint4 sb1 = *(const uint4*)(bb(0) + 8);

    for (int s = 0; s < 16; ++s) {
        __syncthreads();
        *(uint4*)(&As[row * 72 + kk]) = sa0;
        *(uint4*)(&As[row * 72 + kk + 8]) = sa1;
        *(uint4*)(&Bs[row * 72 + kk]) = sb0;
        *(uint4*)(&Bs[row * 72 + kk + 8]) = sb1;
        __syncthreads();
        if (s + 1 < 16) {
            const u16* ap = aa(s + 1);
            const u16* bp = bb(s + 1);
            sa0 = *(const uint4*)ap;
            sa1 = *(const uint4*)(ap + 8);
            sb0 = *(const uint4*)bp;
            sb1 = *(const uint4*)(bp + 8);
        }
#pragma unroll
        for (int k2 = 0; k2 < 64; k2 += 32) {
            const int ko = k2 + quad * 8;
            const short8 fa0 = *(const short8*)(&As[(wr + l16) * 72 + ko]);
            const short8 fa1 = *(const short8*)(&As[(wr + 16 + l16) * 72 + ko]);
            const short8 fb0 = *(const short8*)(&Bs[(wc + l16) * 72 + ko]);
            const short8 fb1 = *(const short8*)(&Bs[(wc + 16 + l16) * 72 + ko]);
            acc[0][0] = __builtin_amdgcn_mfma_f32_16x16x32_bf16(fa0, fb0, acc[0][0], 0, 0, 0);
            acc[0][1] = __builtin_amdgcn_mfma_f32_16x16x32_bf16(fa0, fb1, acc[0][1], 0, 0, 0);
            acc[1][0] = __builtin_amdgcn_mfma_f32_16x16x32_bf16(fa1, fb0, acc[1][0], 0, 0, 0);
            acc[1][1] = __builtin_amdgcn_mfma_f32_16x16x32_bf16(fa1, fb1, acc[1][1], 0, 0, 0);
        }
    }

#pragma unroll
    for (int m = 0; m < 2; ++m)
#pragma unroll
        for (int n = 0; n < 2; ++n)
#pragma unroll
            for (int r = 0; r < 4; ++r) {
                const int rowl = wr + 16 * m + quad * 4 + r;
                const int coll = wc + 16 * n + l16;
                const size_t idx = stBase + (size_t)rowl * Hh + coll;
                out[idx] += acc[m][n][r];
            }
}

extern "C" void kernel_launch(void* const* d_in, const int* in_sizes, int n_in,
                              void* d_out, int out_size, void* d_ws, size_t ws_size,
                              hipStream_t stream) {
    const float* h = (const float*)d_in[0];       // [4,256,768] fp32
    const int* rels = (const int*)d_in[1];        // [4,256,256] i32
    const float* basic = (const float*)d_in[2];   // [4,768,768] fp32
    const float* relw = (const float*)d_in[3];    // [64,4] fp32
    const float* selfw = (const float*)d_in[4];   // [768,768] fp32 (out,in)
    float* out = (float*)d_out;                   // [4,256,768] fp32

    // ws layout (u16 elems, 16B-aligned)
    u16* basicT = (u16*)d_ws;                          // 2,359,296
    u16* coefC = basicT + (size_t)4 * Hh * Hh;         // 1,048,576
    u16* Gt = coefC + (size_t)Bb * 4 * Ss * Ss;        // 3,145,728  [bk][o][j]
    u16* hbf = Gt + (size_t)Bb * 4 * Hh * Ss;          //   786,432
    u16* swbf = hbf + (size_t)Bb * Ss * Hh;            //   589,824

    k_prep<<<4672, 256, 0, stream>>>(h, rels, basic, relw, selfw, basicT, coefC, hbf, swbf);
    k_mid<<<960, 256, 0, stream>>>(basicT, hbf, swbf, Gt, out);
    k_phase2<<<192, 256, 0, stream>>>(coefC, Gt, out);
}